// Round 8
// baseline (267.002 us; speedup 1.0000x reference)
//
#include <hip/hip_runtime.h>

// SparseMaxPool — R15. Four structurally different kernels (R7/R9/R11/R14:
// 1-wave shfl, 1-wave prologue-loaded, 1-wave DPP, 4-wave coop @32 waves/CU)
// all land at 95-105 us => ~2.8 TB/s effective write BW, structure-invariant,
// while fillBufferAligned sustains 6.5 TB/s on the SAME buffer. Occupancy,
// chain latency, vmcnt coupling, barriers: all falsified. Remaining theory:
// L2 write-allocation wall — our stores allocate in the per-XCD L2; the blit
// fill streams past it. R11's nontemporal probe was confounded (slow node;
// 'nt' alone still allocates). gfx950 lever: sc0 sc1 nt on global_store =
// system-scope streaming, no L2 allocate (gfx940+ replacement for glc/slc).
//
// R15 = R11 with ONE change: emit stores via inline asm
//   global_store_dwordx4 vaddr, vdata, off sc0 sc1 nt
// plus an explicit end-of-kernel s_waitcnt vmcnt(0) (asm stores may not be
// counted by the compiler's epilogue drain). Everything else identical to
// R11: 16 KB tile zeroed once, DPP chain, 4112 blocks x 4 tiles, prologue
// loads, no barriers, 10 blocks/CU.

typedef float vfloat4 __attribute__((ext_vector_type(4)));

constexpr int S_LEN[31] = {
  63,62,61,60,59,58,57,56,55,54,53,52,51,50,49,
  24,23,22,21,20,19,18,17,
  8,7,6,5,4,3,2,1};
constexpr int S_ST[31] = {
  1,1,1,1,1,1,1,1,1,1,1,1,1,1,1,
  2,2,2,2,2,2,2,2,
  4,4,4,4,4,4,4,4};
constexpr int S_OFF[31] = {
  1,2,3,4,5,6,7,8,9,10,11,12,13,14,15,
  17,19,21,23,25,27,29,31,
  35,39,43,47,51,55,59,63};

// DPP move: CTRL=0x130 wave_shl:1 (lane i <- i+1), 0xB1 quad_perm [1,0,3,2]
// (lane i <- i^1). Full masks, bound_ctrl=0-fill. Verified absmax 0.0 (R11).
template <int CTRL>
__device__ __forceinline__ float dpp_movf(float v) {
  return __int_as_float(
      __builtin_amdgcn_update_dpp(0, __float_as_int(v), CTRL, 0xF, 0xF, true));
}

// Streaming store: no L2 allocation (sc0 sc1 = system scope, nt = stream).
__device__ __forceinline__ void store_stream(vfloat4* p, vfloat4 v) {
  asm volatile("global_store_dwordx4 %0, %1, off sc0 sc1 nt"
               :: "v"(p), "v"(v) : "memory");
}

__device__ __forceinline__ void process_tile(float* __restrict__ tile, int lane,
                                             float curx,
                                             float* __restrict__ optr) {
  // Diagonal (bank = lane%32, 2-way across the wave = free).
  tile[lane * 65] = curx;

  float cur = curx;
#pragma unroll
  for (int m = 0; m < 31; ++m) {
    if (m == 15 || m == 23) {             // k=3, s=2
      float a = fmaxf(cur, dpp_movf<0x130>(cur));  // a[l]=max(c[l],c[l+1])
      float u = fmaxf(a, dpp_movf<0xB1>(a));       // u[l]=max(a[l],a[l^1])
      cur = __shfl(u, 2 * lane);                   // cur[l]=u[2l]
    } else {                              // k=2, s=1 — pure-VALU DPP
      cur = fmaxf(cur, dpp_movf<0x130>(cur));
    }
    if (lane < S_LEN[m]) tile[lane * (S_ST[m] * 65) + S_OFF[m]] = cur;
  }

  // Emit: 16x (ds_read_b128 + streaming global_store_dwordx4), coalesced,
  // fixed LDS addresses. Per-wave DS ordering makes next tile's scatter safe.
  vfloat4* o4 = (vfloat4*)optr;
  const vfloat4* t4 = (const vfloat4*)tile;
#pragma unroll
  for (int it = 0; it < 16; ++it) {
    vfloat4 v = t4[it * 64 + lane];
    store_stream(&o4[it * 64 + lane], v);
  }
}

__global__ void __launch_bounds__(64)
sparse_pool_kernel(const float* __restrict__ x, float* __restrict__ out,
                   int nrows, int ntiles) {
  __shared__ float tile[4096];            // 16 KB -> 10 blocks/CU
  const int lane = threadIdx.x;
  const int t0 = blockIdx.x;
  const int stride = gridDim.x;

  // Prologue: issue ALL input loads now (4 independent global loads, issued
  // BEFORE any store => their vmcnt waits are counted, never store drains).
  float xv0 = 1.0f, xv1 = 1.0f, xv2 = 1.0f, xv3 = 1.0f;
  if (t0 < nrows)                xv0 = x[(size_t)t0 * 64 + lane];
  if (t0 + stride < nrows)       xv1 = x[((size_t)t0 + stride) * 64 + lane];
  if (t0 + 2 * stride < nrows)   xv2 = x[((size_t)t0 + 2 * stride) * 64 + lane];
  if (t0 + 3 * stride < nrows)   xv3 = x[((size_t)t0 + 3 * stride) * 64 + lane];

  // Zero the tile ONCE (overlaps the loads). Valid positions are overwritten
  // every tile; the zero background persists (valid set is tile-invariant).
  const vfloat4 z = {0.f, 0.f, 0.f, 0.f};
#pragma unroll
  for (int i = 0; i < 16; ++i)
    ((vfloat4*)tile)[i * 64 + lane] = z;

  // Steady state: zero global loads -> no load-side vmcnt waits.
  if (t0 < ntiles)
    process_tile(tile, lane, xv0, out + (size_t)t0 * 4096);
  if (t0 + stride < ntiles)
    process_tile(tile, lane, xv1, out + ((size_t)t0 + stride) * 4096);
  if (t0 + 2 * stride < ntiles)
    process_tile(tile, lane, xv2, out + ((size_t)t0 + 2 * stride) * 4096);
  if (t0 + 3 * stride < ntiles)
    process_tile(tile, lane, xv3, out + ((size_t)t0 + 3 * stride) * 4096);

  // Asm-issued stores may not be counted in the compiler's epilogue drain;
  // make completion explicit before end-of-kernel release.
  asm volatile("s_waitcnt vmcnt(0)" ::: "memory");
}

extern "C" void kernel_launch(void* const* d_in, const int* in_sizes, int n_in,
                              void* d_out, int out_size, void* d_ws, size_t ws_size,
                              hipStream_t stream) {
  const float* x = (const float*)d_in[0];        // fp32 input (32,512,64)
  float* out = (float*)d_out;                    // fp32 output

  const int nx     = in_sizes[0];                // B*D*64 = 1048576
  const int nrows  = nx / 64;                    // 16384 map tiles
  const int ntiles = out_size / 4096;            // 16448 = map + mask tiles

  // Exactly 4 tiles per block (4112 * 4 = 16448): uniform block duration,
  // prologue-loaded inputs, 10 blocks/CU resident (160 KB LDS exact fit).
  const int blocks = (ntiles + 3) / 4;
  sparse_pool_kernel<<<dim3(blocks), 64, 0, stream>>>(x, out, nrows, ntiles);
}

// Round 9
// 261.856 us; speedup vs baseline: 1.0196x; 1.0196x over previous
//
#include <hip/hip_runtime.h>

// SparseMaxPool — R16. Five structure-invariant nulls (chain/DPP, occupancy
// 10->32, vmcnt, barriers, sc0sc1nt) => the measurement model was wrong.
// Re-audit: poison fill writes 1.076 GB = 65,792 x 16 KB tiles = out_size/4096
// IF out_size is in ELEMENTS. Then ntiles=65,792, our kernel writes 1.078 GB
// (same as fill) at ~4.15 TB/s over ~260 us, and 49,408 tiles (75%!) are
// IDENTICAL mask tiles each redundantly running chain+LDS round-trips.
//
// R16 = R9 (best, 259.4) + mask-tile fast path: tiles >= nrows emit the
// compile-time-constant mask pattern straight from registers (closed-form
// validity predicate, HW-verified by R8's absmax 0.0) — no input load, no
// chain, no LDS. Pure coalesced dwordx4 stores => fill-like throughput.
// Discriminator built in: if ntiles is really 16,448 (bytes reading), only
// 64/16,448 tiles take the fast path => null result, bytes-reading confirmed.

typedef float vfloat4 __attribute__((ext_vector_type(4)));

constexpr int S_LEN[31] = {
  63,62,61,60,59,58,57,56,55,54,53,52,51,50,49,
  24,23,22,21,20,19,18,17,
  8,7,6,5,4,3,2,1};
constexpr int S_ST[31] = {
  1,1,1,1,1,1,1,1,1,1,1,1,1,1,1,
  2,2,2,2,2,2,2,2,
  4,4,4,4,4,4,4,4};
constexpr int S_OFF[31] = {
  1,2,3,4,5,6,7,8,9,10,11,12,13,14,15,
  17,19,21,23,25,27,29,31,
  35,39,43,47,51,55,59,63};

// DPP move: CTRL=0x130 wave_shl:1 (lane i <- i+1), 0xB1 quad_perm [1,0,3,2]
// (lane i <- i^1). Full masks, bound_ctrl=0-fill. Verified absmax 0.0 (R11).
template <int CTRL>
__device__ __forceinline__ float dpp_movf(float v) {
  return __int_as_float(
      __builtin_amdgcn_update_dpp(0, __float_as_int(v), CTRL, 0xF, 0xF, true));
}

// Closed-form validity of output position (r,c) — HW-verified in R8
// (cidx_of's default-zero complement; absmax 0.0).
__device__ __forceinline__ bool valid_pos(int r, int c) {
  const int off = c - r;
  if (off == 0) return true;                                   // diagonal
  if (off >= 1 && off <= 15) return true;                      // st=1 stages
  if (off >= 17 && off <= 31 && (off & 1) && !(r & 1)) return true;   // st=2
  if (off >= 35 && off <= 63 && !((off - 35) & 3) && !(r & 3)) return true; // st=4
  return false;
}

// Mask tile: constant pattern, emitted straight from registers. No input,
// no chain, no LDS — pure coalesced stores (fill-shaped).
__device__ __forceinline__ void emit_mask(int lane, float* __restrict__ optr) {
  vfloat4* o4 = (vfloat4*)optr;
  const int rbase = lane >> 4;
  const int c0 = (lane & 15) * 4;
#pragma unroll
  for (int it = 0; it < 16; ++it) {
    const int r = it * 4 + rbase;
    vfloat4 v = { valid_pos(r, c0 + 0) ? 1.f : 0.f,
                  valid_pos(r, c0 + 1) ? 1.f : 0.f,
                  valid_pos(r, c0 + 2) ? 1.f : 0.f,
                  valid_pos(r, c0 + 3) ? 1.f : 0.f };
    o4[it * 64 + lane] = v;
  }
}

// Map tile: unchanged R9/R11 data path (DPP chain + conflict-free scatter +
// ds_read_b128 emit). Verified absmax 0.0.
__device__ __forceinline__ void process_tile(float* __restrict__ tile, int lane,
                                             float curx,
                                             float* __restrict__ optr) {
  tile[lane * 65] = curx;                 // diagonal (2-way bank = free)

  float cur = curx;
#pragma unroll
  for (int m = 0; m < 31; ++m) {
    if (m == 15 || m == 23) {             // k=3, s=2
      float a = fmaxf(cur, dpp_movf<0x130>(cur));  // a[l]=max(c[l],c[l+1])
      float u = fmaxf(a, dpp_movf<0xB1>(a));       // u[l]=max(a[l],a[l^1])
      cur = __shfl(u, 2 * lane);                   // cur[l]=u[2l]
    } else {                              // k=2, s=1 — pure-VALU DPP
      cur = fmaxf(cur, dpp_movf<0x130>(cur));
    }
    if (lane < S_LEN[m]) tile[lane * (S_ST[m] * 65) + S_OFF[m]] = cur;
  }

  vfloat4* o4 = (vfloat4*)optr;
  const vfloat4* t4 = (const vfloat4*)tile;
#pragma unroll
  for (int it = 0; it < 16; ++it)
    o4[it * 64 + lane] = t4[it * 64 + lane];
}

__global__ void __launch_bounds__(64)
sparse_pool_kernel(const float* __restrict__ x, float* __restrict__ out,
                   int nrows, int ntiles) {
  __shared__ float tile[4096];            // 16 KB -> 10 blocks/CU
  const int lane = threadIdx.x;
  const int t0 = blockIdx.x;
  const int stride = gridDim.x;

  // Prologue: issue map-tile input loads up front (mask tiles load nothing).
  float xv0 = 1.0f, xv1 = 1.0f, xv2 = 1.0f, xv3 = 1.0f;
  if (t0 < nrows)                xv0 = x[(size_t)t0 * 64 + lane];
  if (t0 + stride < nrows)       xv1 = x[((size_t)t0 + stride) * 64 + lane];
  if (t0 + 2 * stride < nrows)   xv2 = x[((size_t)t0 + 2 * stride) * 64 + lane];
  if (t0 + 3 * stride < nrows)   xv3 = x[((size_t)t0 + 3 * stride) * 64 + lane];

  // Zero the tile ONCE (overlaps loads). Zero background persists across
  // map tiles (valid-position set is tile-invariant).
  const vfloat4 z = {0.f, 0.f, 0.f, 0.f};
#pragma unroll
  for (int i = 0; i < 16; ++i)
    ((vfloat4*)tile)[i * 64 + lane] = z;

  // 4 assigned tiles; per-tile branch is block-uniform. Map tiles use the
  // proven LDS path; mask tiles (t >= nrows) stream the constant pattern.
  {
    const long long t = t0;
    if (t < ntiles) {
      if (t < nrows) process_tile(tile, lane, xv0, out + (size_t)t * 4096);
      else           emit_mask(lane, out + (size_t)t * 4096);
    }
  }
  {
    const long long t = t0 + (long long)stride;
    if (t < ntiles) {
      if (t < nrows) process_tile(tile, lane, xv1, out + (size_t)t * 4096);
      else           emit_mask(lane, out + (size_t)t * 4096);
    }
  }
  {
    const long long t = t0 + 2LL * stride;
    if (t < ntiles) {
      if (t < nrows) process_tile(tile, lane, xv2, out + (size_t)t * 4096);
      else           emit_mask(lane, out + (size_t)t * 4096);
    }
  }
  {
    const long long t = t0 + 3LL * stride;
    if (t < ntiles) {
      if (t < nrows) process_tile(tile, lane, xv3, out + (size_t)t * 4096);
      else           emit_mask(lane, out + (size_t)t * 4096);
    }
  }
}

extern "C" void kernel_launch(void* const* d_in, const int* in_sizes, int n_in,
                              void* d_out, int out_size, void* d_ws, size_t ws_size,
                              hipStream_t stream) {
  const float* x = (const float*)d_in[0];        // fp32 input (32,512,64)
  float* out = (float*)d_out;                    // fp32 output

  const int nx     = in_sizes[0];                // 1048576 elements
  const int nrows  = nx / 64;                    // 16384 map tiles (verified)
  const int ntiles = out_size / 4096;            // 16448 (bytes) or 65792 (elems)

  // Exactly 4 tiles per block, strided assignment (map work balanced across
  // blocks under either ntiles reading).
  const int blocks = (ntiles + 3) / 4;
  sparse_pool_kernel<<<dim3(blocks), 64, 0, stream>>>(x, out, nrows, ntiles);
}